// Round 12
// baseline (408.398 us; speedup 1.0000x reference)
//
#include <hip/hip_runtime.h>

#define BB 256
#define SS 1024
#define TT 128
#define EN 127          // END state (row EN of trans = -1e4)
#define IMIN -10000.0f
#define L2E 1.4426950408889634f
#define LN2f 0.6931471805599453f
#define CS 20           // chunk stride (floats): 16 data + 4 pad.
                        // banks (20c+4k)%32 cover all 32 banks exactly once
                        // per read instr -> zero conflicts; mapping bijective
                        // (r11's 8c+4*((c>>2)&1) was NOT -> absmax 128).

// pure-DPP 8-lane butterfly (VALU pipe only; shfl_xor(,4) would lower to
// ds_swizzle = DS pipe). xor1/xor2 = quad_perm, "xor4" via row_half_mirror
// (after xor1+xor2 every quad holds the quad-sum, mirror adds other quad).
template<int CTRL>
__device__ __forceinline__ float dpp_mov(float x) {
    return __int_as_float(__builtin_amdgcn_update_dpp(
        0, __float_as_int(x), CTRL, 0xF, 0xF, true));
}
__device__ __forceinline__ float sum8(float x) {
    x += dpp_mov<0xB1>(x);    // quad_perm [1,0,3,2]
    x += dpp_mov<0x4E>(x);    // quad_perm [2,3,0,1]
    x += dpp_mov<0x141>(x);   // row_half_mirror
    return x;
}
__device__ __forceinline__ float max8(float x) {
    x = fmaxf(x, dpp_mov<0xB1>(x));
    x = fmaxf(x, dpp_mov<0x4E>(x));
    x = fmaxf(x, dpp_mov<0x141>(x));
    return x;
}

// One block per batch, 256 threads (4 waves, 1/SIMD -> no co-resident issue
// serialization; r8-r11's 870cy/step = 2 waves/SIMD issue + fixed chain).
// tid = 8g + c: g = row-group (rows 4g..4g+3), c = j-chunk (cols 16c..16c+15).
// Per thread: 4x16 tile = 64 FMA, 4 ds_read_b128 (v) + 1 (feat).
// v[j]=2^(A[j]-sh) in LDS; anchor shift dsh=log2(v[0]) (uniform, no reduce).
// Step barrier = lgkmcnt-only (HBM prefetch stays in flight).
__global__ __launch_bounds__(256, 1) void crf_fwd(const float* __restrict__ feats,
                                                  const int* __restrict__ blen,
                                                  const float* __restrict__ trans,
                                                  float* __restrict__ out)
{
    const int tid = threadIdx.x;
    const int c   = tid & 7;     // j-chunk
    const int g   = tid >> 3;    // row-group
    const int b   = blockIdx.x;

    __shared__ __align__(16) float vst[2][8 * CS];     // 160 floats each
    __shared__ __align__(16) float featbuf[2][8 * TT];
    __shared__ __align__(16) float wout[TT];
    __shared__ __align__(16) float red[8];

    const float* fb = feats + (size_t)b * (SS * TT);
    const int L = blen[b];

    // stage feature chunk 0 (steps 0..7): 256 threads x float4 = 1024 floats
    *(float4*)(&featbuf[0][tid * 4]) = *(const float4*)(fb + tid * 4);

    // P tile rows 4g..4g+3 x cols 16c..16c+15, base-2 units
    float4 P[4][4];
    {
        const float* tb = trans + (4 * g) * TT + 16 * c;
        #pragma unroll
        for (int m = 0; m < 4; ++m)
            #pragma unroll
            for (int k = 0; k < 4; ++k) {
                float4 t = *(const float4*)(tb + m * TT + 4 * k);
                t.x *= L2E; t.y *= L2E; t.z *= L2E; t.w *= L2E;
                P[m][k] = t;
            }
    }
    // per-row full-row max / normalize / sum (8-lane DPP reductions)
    float rm[4], S[4];
    #pragma unroll
    for (int m = 0; m < 4; ++m) {
        float r = -3.4e38f;
        #pragma unroll
        for (int k = 0; k < 4; ++k)
            r = fmaxf(r, fmaxf(fmaxf(P[m][k].x, P[m][k].y),
                               fmaxf(P[m][k].z, P[m][k].w)));
        rm[m] = max8(r);
        float s = 0.f;
        #pragma unroll
        for (int k = 0; k < 4; ++k) {
            P[m][k].x = exp2f(P[m][k].x - rm[m]);
            P[m][k].y = exp2f(P[m][k].y - rm[m]);
            P[m][k].z = exp2f(P[m][k].z - rm[m]);
            P[m][k].w = exp2f(P[m][k].w - rm[m]);
            s += (P[m][k].x + P[m][k].y) + (P[m][k].z + P[m][k].w);
        }
        S[m] = sum8(s);
    }

    // exact step 0 (alpha0 = delta on START, col START = -1e4 -> all scores
    // ~ -1e4): A1 = f0*L2E + IMIN*L2E + log2(1 + sum_j 2^T2_ij), anchored at
    // rmc=max(rm,0) so row EN (rm=-14427) degrades gracefully (r4 fix).
    float4 f0v = *(const float4*)(fb + 4 * g);
    float f0a[4] = {f0v.x, f0v.y, f0v.z, f0v.w};
    float A1[4];
    #pragma unroll
    for (int m = 0; m < 4; ++m) {
        float rmc = fmaxf(rm[m], 0.f);
        A1[m] = fmaf(f0a[m], L2E, (IMIN * L2E) + rmc +
                     log2f(fmaf(S[m], exp2f(rm[m] - rmc), exp2f(-rmc))));
    }

    if (tid == 0) red[0] = A1[0];   // anchor = state 0 (tid0: g=0 -> row 0)
    __syncthreads();                // also covers featbuf[0] staging
    float sh = red[0];
    if (c == 0) {
        float4 v0w = make_float4(exp2f(A1[0] - sh), exp2f(A1[1] - sh),
                                 exp2f(A1[2] - sh), exp2f(A1[3] - sh));
        *(float4*)(&vst[0][CS * (g >> 2) + 4 * (g & 3)]) = v0w;
    }
    __syncthreads();

    int cur = 0;
    float4 fnx = *(const float4*)(fb + 8 * TT + tid * 4);  // prefetch chunk 1

    for (int ch = 0; ; ++ch) {
        if (8 * ch + 8 < L) {
            // stage chunk ch+1 into the idle buffer (>=7 step barriers order
            // it before first read); issue prefetch of chunk ch+2
            *(float4*)(&featbuf[(ch + 1) & 1][tid * 4]) = fnx;
            int cn = min(8 * ch + 16, SS - 8);
            fnx = *(const float4*)(fb + cn * TT + tid * 4);
        }
        const int sLo = (ch == 0) ? 1 : 8 * ch;
        const int sHi = min(8 * ch + 8, L);
        for (int s = sLo; s < sHi; ++s) {
            const float* vp = &vst[cur][CS * c];
            float  v0f = vst[cur][0];
            float4 ff  = *(const float4*)(&featbuf[ch & 1][((s & 7) << 7) + 4 * g]);
            float4 v0  = *(const float4*)(vp);
            float4 v1  = *(const float4*)(vp + 4);
            float4 v2  = *(const float4*)(vp + 8);
            float4 v3  = *(const float4*)(vp + 12);

            float dsh = log2f(v0f);
            float ffa[4] = {ff.x, ff.y, ff.z, ff.w};

            float vnv[4];
            #pragma unroll
            for (int m = 0; m < 4; ++m) {
                float a0 = P[m][0].x * v0.x, a1 = P[m][0].y * v0.y;
                float a2 = P[m][0].z * v0.z, a3 = P[m][0].w * v0.w;
                a0 = fmaf(P[m][1].x, v1.x, a0); a1 = fmaf(P[m][1].y, v1.y, a1);
                a2 = fmaf(P[m][1].z, v1.z, a2); a3 = fmaf(P[m][1].w, v1.w, a3);
                a0 = fmaf(P[m][2].x, v2.x, a0); a1 = fmaf(P[m][2].y, v2.y, a1);
                a2 = fmaf(P[m][2].z, v2.z, a2); a3 = fmaf(P[m][2].w, v2.w, a3);
                a0 = fmaf(P[m][3].x, v3.x, a0); a1 = fmaf(P[m][3].y, v3.y, a1);
                a2 = fmaf(P[m][3].z, v3.z, a2); a3 = fmaf(P[m][3].w, v3.w, a3);
                float t = sum8(((a0 + a1) + (a2 + a3)));
                float cf = exp2f(fmaf(ffa[m], L2E, rm[m] - dsh));
                vnv[m] = cf * t;
            }
            sh += dsh;
            if (c == 0)
                *(float4*)(&vst[cur ^ 1][CS * (g >> 2) + 4 * (g & 3)]) =
                    make_float4(vnv[0], vnv[1], vnv[2], vnv[3]);
            // lgkmcnt-only barrier: don't drain the global prefetch
            asm volatile("s_waitcnt lgkmcnt(0)\n\ts_barrier" ::: "memory");
            cur ^= 1;
        }
        if (8 * ch + 8 >= L) break;
    }

    __syncthreads();
    // epilogue: out = ln2 * log2 sum_j 2^(sh + log2 v_j + trans[EN][j]*L2E)
    if (tid < TT) {
        int j = tid;
        float vL = vst[cur][CS * (j >> 4) + (j & 15)];
        wout[j] = fmaf(trans[EN * TT + j], L2E, sh + log2f(vL)); // v=0 -> -inf ok
    }
    __syncthreads();
    if (tid < 64) {
        float w0 = wout[tid], w1 = wout[tid + 64];
        float mm = fmaxf(w0, w1);
        #pragma unroll
        for (int off = 1; off < 64; off <<= 1) mm = fmaxf(mm, __shfl_xor(mm, off));
        float ss = exp2f(w0 - mm) + exp2f(w1 - mm);
        #pragma unroll
        for (int off = 1; off < 64; off <<= 1) ss += __shfl_xor(ss, off);
        if (tid == 0) out[b] = (mm + log2f(ss)) * LN2f;
    }
}

extern "C" void kernel_launch(void* const* d_in, const int* in_sizes, int n_in,
                              void* d_out, int out_size, void* d_ws, size_t ws_size,
                              hipStream_t stream) {
    const float* feats = (const float*)d_in[0];
    const int*   blen  = (const int*)d_in[1];
    const float* trans = (const float*)d_in[2];
    float*       o     = (float*)d_out;
    crf_fwd<<<dim3(BB), dim3(256), 0, stream>>>(feats, blen, trans, o);
}

// Round 13
// 389.038 us; speedup vs baseline: 1.0498x; 1.0498x over previous
//
#include <hip/hip_runtime.h>

#define BB 256
#define SS 1024
#define TT 128
#define EN 127          // END state (row EN of trans = -1e4)
#define IMIN -10000.0f
#define L2E 1.4426950408889634f
#define LN2f 0.6931471805599453f
#define CS 20           // chunk stride (floats): 16 data + 4 pad; banks
                        // (20c+4k)%32 cover all 32 banks once per instr;
                        // bijective (r12-verified, absmax 0)

// pure-DPP 8-lane butterfly (VALU only; verified in r12)
template<int CTRL>
__device__ __forceinline__ float dpp_mov(float x) {
    return __int_as_float(__builtin_amdgcn_update_dpp(
        0, __float_as_int(x), CTRL, 0xF, 0xF, true));
}
__device__ __forceinline__ float sum8(float x) {
    x += dpp_mov<0xB1>(x);    // quad_perm [1,0,3,2]
    x += dpp_mov<0x4E>(x);    // quad_perm [2,3,0,1]
    x += dpp_mov<0x141>(x);   // row_half_mirror
    return x;
}
__device__ __forceinline__ float max8(float x) {
    x = fmaxf(x, dpp_mov<0xB1>(x));
    x = fmaxf(x, dpp_mov<0x4E>(x));
    x = fmaxf(x, dpp_mov<0x141>(x));
    return x;
}

// Model (r3..r12): step = max(LDS-pipe slots, SIMD issue, chain).
// r8: 8 waves x ~10 DS-instr x ~10cy ~ 800cy (pipe-bound, redundant bcast).
// r12: tiled (few DS) but 1 wave/SIMD exposed the chain (956cy).
// Here: tiled 2x16 (5 DS reads/thread) AND 512 thr (2 waves/SIMD).
// tid = 8*rp + c: rp = row-pair (states 2rp,2rp+1), c = 16-col chunk.
// Chain cuts: v0 via readfirstlane of c==0 lanes' v0.x (no extra DS read);
// rescale by rcp(v0) (no log2->exp2 on chain); ef=exp2(f*L2E+rm) off-chain;
// sh += log2(v0) lazy. Step barrier = lgkmcnt-only (prefetch stays in flight).
__global__ __launch_bounds__(512, 1) void crf_fwd(const float* __restrict__ feats,
                                                  const int* __restrict__ blen,
                                                  const float* __restrict__ trans,
                                                  float* __restrict__ out)
{
    const int tid = threadIdx.x;
    const int c   = tid & 7;     // j-chunk (cols 16c..16c+15)
    const int rp  = tid >> 3;    // row pair: states 2rp, 2rp+1
    const int b   = blockIdx.x;

    __shared__ __align__(16) float vst[2][8 * CS];
    __shared__ __align__(16) float featbuf[2][8 * TT];
    __shared__ __align__(16) float wout[TT];
    __shared__ __align__(16) float red[8];

    const float* fb = feats + (size_t)b * (SS * TT);
    const int L = blen[b];

    // stage feature chunk 0: 512 threads x float2 = 1024 floats
    *(float2*)(&featbuf[0][tid * 2]) = *(const float2*)(fb + tid * 2);

    // P tile: rows 2rp,2rp+1 x cols 16c..16c+15, base-2 units
    const float* tb = trans + (2 * rp) * TT + 16 * c;
    float4 Pa0 = *(const float4*)(tb);
    float4 Pa1 = *(const float4*)(tb + 4);
    float4 Pa2 = *(const float4*)(tb + 8);
    float4 Pa3 = *(const float4*)(tb + 12);
    float4 Pb0 = *(const float4*)(tb + TT);
    float4 Pb1 = *(const float4*)(tb + TT + 4);
    float4 Pb2 = *(const float4*)(tb + TT + 8);
    float4 Pb3 = *(const float4*)(tb + TT + 12);
#define SC4(Pv) Pv.x *= L2E; Pv.y *= L2E; Pv.z *= L2E; Pv.w *= L2E
    SC4(Pa0); SC4(Pa1); SC4(Pa2); SC4(Pa3);
    SC4(Pb0); SC4(Pb1); SC4(Pb2); SC4(Pb3);
#undef SC4
#define LMAX4(Pv) fmaxf(fmaxf(Pv.x, Pv.y), fmaxf(Pv.z, Pv.w))
    float rm0 = max8(fmaxf(fmaxf(LMAX4(Pa0), LMAX4(Pa1)),
                           fmaxf(LMAX4(Pa2), LMAX4(Pa3))));
    float rm1 = max8(fmaxf(fmaxf(LMAX4(Pb0), LMAX4(Pb1)),
                           fmaxf(LMAX4(Pb2), LMAX4(Pb3))));
#undef LMAX4
#define NRM4(Pv, r) Pv.x = exp2f(Pv.x - r); Pv.y = exp2f(Pv.y - r); \
                    Pv.z = exp2f(Pv.z - r); Pv.w = exp2f(Pv.w - r)
    NRM4(Pa0, rm0); NRM4(Pa1, rm0); NRM4(Pa2, rm0); NRM4(Pa3, rm0);
    NRM4(Pb0, rm1); NRM4(Pb1, rm1); NRM4(Pb2, rm1); NRM4(Pb3, rm1);
#undef NRM4
#define SUM4(Pv) ((Pv.x + Pv.y) + (Pv.z + Pv.w))
    float S0 = sum8((SUM4(Pa0) + SUM4(Pa1)) + (SUM4(Pa2) + SUM4(Pa3)));
    float S1 = sum8((SUM4(Pb0) + SUM4(Pb1)) + (SUM4(Pb2) + SUM4(Pb3)));
#undef SUM4

    // exact step 0 (alpha0 = delta on START, col START = -1e4 -> all scores
    // ~ -1e4): A1 = f0*L2E + IMIN*L2E + log2(1 + sum_j 2^T2_ij), anchored at
    // rmc=max(rm,0) so row EN (rm=-14427) degrades gracefully (r4 fix).
    float2 f0v = *(const float2*)(fb + 2 * rp);
    float rmc0 = fmaxf(rm0, 0.f), rmc1 = fmaxf(rm1, 0.f);
    float A1a = fmaf(f0v.x, L2E, (IMIN * L2E) + rmc0 +
                     log2f(fmaf(S0, exp2f(rm0 - rmc0), exp2f(-rmc0))));
    float A1b = fmaf(f0v.y, L2E, (IMIN * L2E) + rmc1 +
                     log2f(fmaf(S1, exp2f(rm1 - rmc1), exp2f(-rmc1))));

    if (tid == 0) red[0] = A1a;   // anchor = state 0
    __syncthreads();              // also covers featbuf[0] staging
    float sh = red[0];
    if (c == 0)
        *(float2*)(&vst[0][CS * (rp >> 3) + 2 * (rp & 7)]) =
            make_float2(exp2f(A1a - sh), exp2f(A1b - sh));  // v[0]==1
    __syncthreads();

    int cur = 0;
    float2 fnx = *(const float2*)(fb + 8 * TT + tid * 2);  // prefetch chunk 1

    for (int ch = 0; ; ++ch) {
        if (8 * ch + 8 < L) {
            // stage chunk ch+1 into the idle buffer (>=7 step barriers order
            // it before first read); issue prefetch of chunk ch+2
            *(float2*)(&featbuf[(ch + 1) & 1][tid * 2]) = fnx;
            int cn = min(8 * ch + 16, SS - 8);
            fnx = *(const float2*)(fb + cn * TT + tid * 2);
        }
        const int sLo = (ch == 0) ? 1 : 8 * ch;
        const int sHi = min(8 * ch + 8, L);
        for (int s = sLo; s < sHi; ++s) {
            const float* vp = &vst[cur][CS * c];
            float4 v0 = *(const float4*)(vp);
            float4 v1 = *(const float4*)(vp + 4);
            float4 v2 = *(const float4*)(vp + 8);
            float4 v3 = *(const float4*)(vp + 12);
            float2 ffv = *(const float2*)(&featbuf[ch & 1][((s & 7) << 7) + 2 * rp]);

            // lane 0 of each wave has c==0 -> its v0.x IS vst[cur][0]
            float v0u = __int_as_float(
                __builtin_amdgcn_readfirstlane(__float_as_int(v0.x)));
            float rv0 = __builtin_amdgcn_rcpf(v0u);
            float efa = exp2f(fmaf(ffv.x, L2E, rm0)) * rv0;
            float efb = exp2f(fmaf(ffv.y, L2E, rm1)) * rv0;

            float a0 = Pa0.x * v0.x, a1 = Pa0.y * v0.y;
            float a2 = Pa0.z * v0.z, a3 = Pa0.w * v0.w;
            a0 = fmaf(Pa1.x, v1.x, a0); a1 = fmaf(Pa1.y, v1.y, a1);
            a2 = fmaf(Pa1.z, v1.z, a2); a3 = fmaf(Pa1.w, v1.w, a3);
            a0 = fmaf(Pa2.x, v2.x, a0); a1 = fmaf(Pa2.y, v2.y, a1);
            a2 = fmaf(Pa2.z, v2.z, a2); a3 = fmaf(Pa2.w, v2.w, a3);
            a0 = fmaf(Pa3.x, v3.x, a0); a1 = fmaf(Pa3.y, v3.y, a1);
            a2 = fmaf(Pa3.z, v3.z, a2); a3 = fmaf(Pa3.w, v3.w, a3);
            float pa = sum8((a0 + a1) + (a2 + a3));

            float b0 = Pb0.x * v0.x, b1 = Pb0.y * v0.y;
            float b2 = Pb0.z * v0.z, b3 = Pb0.w * v0.w;
            b0 = fmaf(Pb1.x, v1.x, b0); b1 = fmaf(Pb1.y, v1.y, b1);
            b2 = fmaf(Pb1.z, v1.z, b2); b3 = fmaf(Pb1.w, v1.w, b3);
            b0 = fmaf(Pb2.x, v2.x, b0); b1 = fmaf(Pb2.y, v2.y, b1);
            b2 = fmaf(Pb2.z, v2.z, b2); b3 = fmaf(Pb2.w, v2.w, b3);
            b0 = fmaf(Pb3.x, v3.x, b0); b1 = fmaf(Pb3.y, v3.y, b1);
            b2 = fmaf(Pb3.z, v3.z, b2); b3 = fmaf(Pb3.w, v3.w, b3);
            float pb = sum8((b0 + b1) + (b2 + b3));

            float vna = efa * pa, vnb = efb * pb;
            sh += log2f(v0u);      // lazy, off-chain
            if (c == 0)
                *(float2*)(&vst[cur ^ 1][CS * (rp >> 3) + 2 * (rp & 7)]) =
                    make_float2(vna, vnb);
            // lgkmcnt-only barrier: don't drain the global prefetch
            asm volatile("s_waitcnt lgkmcnt(0)\n\ts_barrier" ::: "memory");
            cur ^= 1;
        }
        if (8 * ch + 8 >= L) break;
    }

    __syncthreads();
    // epilogue: out = ln2 * log2 sum_j 2^(sh + log2 v_j + trans[EN][j]*L2E)
    if (tid < TT) {
        int j = tid;
        float vL = vst[cur][CS * (j >> 4) + (j & 15)];
        wout[j] = fmaf(trans[EN * TT + j], L2E, sh + log2f(vL)); // v=0 -> -inf ok
    }
    __syncthreads();
    if (tid < 64) {
        float w0 = wout[tid], w1 = wout[tid + 64];
        float mm = fmaxf(w0, w1);
        #pragma unroll
        for (int off = 1; off < 64; off <<= 1) mm = fmaxf(mm, __shfl_xor(mm, off));
        float ss = exp2f(w0 - mm) + exp2f(w1 - mm);
        #pragma unroll
        for (int off = 1; off < 64; off <<= 1) ss += __shfl_xor(ss, off);
        if (tid == 0) out[b] = (mm + log2f(ss)) * LN2f;
    }
}

extern "C" void kernel_launch(void* const* d_in, const int* in_sizes, int n_in,
                              void* d_out, int out_size, void* d_ws, size_t ws_size,
                              hipStream_t stream) {
    const float* feats = (const float*)d_in[0];
    const int*   blen  = (const int*)d_in[1];
    const float* trans = (const float*)d_in[2];
    float*       o     = (float*)d_out;
    crf_fwd<<<dim3(BB), dim3(512), 0, stream>>>(feats, blen, trans, o);
}